// Round 17
// baseline (268.878 us; speedup 1.0000x reference)
//
#include <hip/hip_runtime.h>

// Problem shapes (fixed by reference setup_inputs)
#define B_DIM 1024
#define C_DIM 128
#define K_DIM 1024
#define E_DIM 4
#define EMBED_ELEMS (B_DIM * C_DIM * E_DIM)
#define NROWS (B_DIM * C_DIM)

typedef float f32x4 __attribute__((ext_vector_type(4)));

// f32 screen: worst-case |d32 - d64| <= ~1e-4; order flip needs f32 gap
// <= 2e-4. THR = 1e-3 gives 5x margin (validated: absmax 0.0 in R15/R16).
#define SCREEN_THR 1e-3f

// d_ws layout: [0] = atomic counter; +4 KB: idx[NROWS]; then list[NROWS].
#define WS_IDX_OFF 1024          // in ints
#define WS_LIST_OFF (1024 + NROWS)

// Grid: 6144 blocks. blockIdx%3==2 -> fill role (2048 blocks x 256 KB);
// else screen role (4096 blocks). Interleaved so every CU hosts both roles.
#define GRID_BLOCKS 6144

__global__ void vq_init(int* ws) { ws[0] = 0; }

// ---------------------------------------------------------------------------
// Mixed kernel: dedicated zero-fill blocks co-resident with screen blocks.
// Fill waves keep the store pipe saturated (rocclr-fill shape, needs ~3-4
// waves/CU); screen waves are pure VALU/LDS -> separate pipes, full overlap.
// ---------------------------------------------------------------------------
__global__ __launch_bounds__(256) void vq_mixed_kernel(
    const float* __restrict__ cw_q,      // (B, C*E) f32
    const float* __restrict__ codebook,  // (C, K, E) f32
    float* __restrict__ out,             // [embed | one_hot]
    int* __restrict__ ws)                // counter / idx / list
{
    __shared__ float4 lds_cb[K_DIM];     // 16 KB (screen role only)

    const int i = blockIdx.x;

    // ---------------- fill role: pure 256 KB zero burst ----------------
    if ((i % 3) == 2) {
        const int f = i / 3;             // 0..2047
        f32x4* dst = (f32x4*)(out + EMBED_ELEMS)
                   + (size_t)f * 16384 + threadIdx.x;
        const f32x4 z = {0.f, 0.f, 0.f, 0.f};
#pragma unroll
        for (int q = 0; q < 64; ++q)     // 64 x 4 KB, contiguous slab
            dst[q * 256] = z;
        return;
    }

    // ---------------- screen role: f32 top-2 argmin ----------------
    const int bid  = (i / 3) * 2 + (i % 3);   // 0..4095 dense
    const int lane = threadIdx.x & 63;
    const int wave = threadIdx.x >> 6;
    const int c      = bid >> 5;         // 32 blocks per c
    const int btile  = bid & 31;
    const int b_base = btile * 32 + wave * 8;

    const float4* cb4 = (const float4*)codebook + (size_t)c * K_DIM;
    const float4* x4  = (const float4*)cw_q;    // (B, C) float4
    float4* emb4 = (float4*)out;                // (B, C) float4
    int* idx_out = ws + WS_IDX_OFF;
    int* list    = ws + WS_LIST_OFF;

    for (int t = threadIdx.x; t < K_DIM; t += 256)
        lds_cb[t] = cb4[t];
    float4 xr[8];
#pragma unroll
    for (int q = 0; q < 8; ++q)
        xr[q] = x4[(size_t)(b_base + q) * C_DIM + c];
    __syncthreads();

    // Per-lane ||b_k||^2 in f32, hoisted.
    float bsqf[16];
#pragma unroll
    for (int j = 0; j < 16; ++j) {
        const float4 cb = lds_cb[j * 64 + lane];
        bsqf[j] = cb.x * cb.x + cb.y * cb.y + cb.z * cb.z + cb.w * cb.w;
    }

    for (int g = 0; g < 2; ++g) {
        float x2f[4][4];
#pragma unroll
        for (int ii = 0; ii < 4; ++ii) {
            const float4 x = xr[g * 4 + ii];
            x2f[ii][0] = -2.0f * x.x;  x2f[ii][1] = -2.0f * x.y;
            x2f[ii][2] = -2.0f * x.z;  x2f[ii][3] = -2.0f * x.w;
        }

        float b1[4], b2[4];  int k1[4];
#pragma unroll
        for (int ii = 0; ii < 4; ++ii) { b1[ii] = INFINITY; b2[ii] = INFINITY; k1[ii] = 0x7fffffff; }

#pragma unroll
        for (int j = 0; j < 16; ++j) {
            const float4 cb = lds_cb[j * 64 + lane];
            const float bsqj = bsqf[j];
            const int k = j * 64 + lane;
#pragma unroll
            for (int ii = 0; ii < 4; ++ii) {
                const float d = fmaf(cb.w, x2f[ii][3],
                                fmaf(cb.z, x2f[ii][2],
                                fmaf(cb.y, x2f[ii][1],
                                fmaf(cb.x, x2f[ii][0], bsqj))));
                const bool  lt1  = d < b1[ii];
                const float old1 = b1[ii];
                b1[ii] = lt1 ? d : old1;
                k1[ii] = lt1 ? k : k1[ii];
                b2[ii] = lt1 ? old1 : fminf(b2[ii], d);
            }
        }

        // Butterfly: global top-2 values + argmin index (32-bit ops).
#pragma unroll
        for (int off = 32; off >= 1; off >>= 1) {
#pragma unroll
            for (int ii = 0; ii < 4; ++ii) {
                const float ob1 = __shfl_xor(b1[ii], off);
                const int   ok1 = __shfl_xor(k1[ii], off);
                const float ob2 = __shfl_xor(b2[ii], off);
                const float mx  = fmaxf(b1[ii], ob1);
                b2[ii] = fminf(mx, fminf(b2[ii], ob2));
                if (ob1 < b1[ii] || (ob1 == b1[ii] && ok1 < k1[ii])) {
                    b1[ii] = ob1; k1[ii] = ok1;
                }
            }
        }

        // Provisional writes; ambiguous rows -> fixup list (~1%).
#pragma unroll
        for (int ii = 0; ii < 4; ++ii) {
            const int b  = b_base + g * 4 + ii;
            const int fk = k1[ii];
            const int r  = b * C_DIM + c;
            if (lane == 0) {
                emb4[r]    = lds_cb[fk];
                idx_out[r] = fk;
                if (!(b2[ii] - b1[ii] > SCREEN_THR)) {
                    const int p = atomicAdd(ws, 1);
                    list[p] = r;
                }
            }
        }
    }
}

// ---------------------------------------------------------------------------
// K_fix: exact f64 re-solve for flagged rows (R3-proven path). One wave/row.
// ---------------------------------------------------------------------------
__global__ __launch_bounds__(256) void vq_fix_kernel(
    const float* __restrict__ cw_q,
    const float* __restrict__ codebook,
    float* __restrict__ out,
    int* __restrict__ ws)
{
    const int lane = threadIdx.x & 63;
    const int wave = threadIdx.x >> 6;
    const int n    = ws[0];
    const int* list = ws + WS_LIST_OFF;
    int* idx_out    = ws + WS_IDX_OFF;
    const float4* x4 = (const float4*)cw_q;
    float4* emb4     = (float4*)out;

    for (int w = blockIdx.x * 4 + wave; w < n; w += gridDim.x * 4) {
        const int r = list[w];
        const int c = r & (C_DIM - 1);
        const float4* cb4 = (const float4*)codebook + (size_t)c * K_DIM;

        const float4 x = x4[r];
        const double x20 = -2.0 * (double)x.x;
        const double x21 = -2.0 * (double)x.y;
        const double x22 = -2.0 * (double)x.z;
        const double x23 = -2.0 * (double)x.w;

        double bd = INFINITY;  int bk = 0x7fffffff;
        for (int j = 0; j < 16; ++j) {
            const float4 cb = cb4[j * 64 + lane];
            const double bx = (double)cb.x, by = (double)cb.y,
                         bz = (double)cb.z, bw = (double)cb.w;
            const double bsqj = bx * bx + by * by + bz * bz + bw * bw;
            const double d = fma(bw, x23, fma(bz, x22,
                             fma(by, x21, fma(bx, x20, bsqj))));
            const int k = j * 64 + lane;
            if (d < bd) { bd = d; bk = k; }
        }
#pragma unroll
        for (int off = 32; off >= 1; off >>= 1) {
            const double od = __shfl_xor(bd, off);
            const int    oi = __shfl_xor(bk, off);
            if (od < bd || (od == bd && oi < bk)) { bd = od; bk = oi; }
        }
        if (lane == 0) {
            emb4[r]    = cb4[bk];
            idx_out[r] = bk;
        }
    }
}

// ---------------------------------------------------------------------------
// K_ones: scatter the 131072 ones (reads final idx, after K_fix).
// ---------------------------------------------------------------------------
__global__ __launch_bounds__(256) void vq_scatter_ones(
    const int* __restrict__ ws,
    float* __restrict__ out)
{
    const int r = blockIdx.x * 256 + threadIdx.x;
    const int k = (ws + WS_IDX_OFF)[r];
    out[EMBED_ELEMS + (size_t)r * K_DIM + k] = 1.0f;
}

extern "C" void kernel_launch(void* const* d_in, const int* in_sizes, int n_in,
                              void* d_out, int out_size, void* d_ws, size_t ws_size,
                              hipStream_t stream) {
    const float* cw_q     = (const float*)d_in[0];
    const float* codebook = (const float*)d_in[1];
    float* out = (float*)d_out;
    int*   ws  = (int*)d_ws;

    vq_init<<<1, 1, 0, stream>>>(ws);
    vq_mixed_kernel<<<GRID_BLOCKS, 256, 0, stream>>>(cw_q, codebook, out, ws);
    vq_fix_kernel<<<256, 256, 0, stream>>>(cw_q, codebook, out, ws);
    vq_scatter_ones<<<NROWS / 256, 256, 0, stream>>>(ws, out);
}

// Round 18
// 260.774 us; speedup vs baseline: 1.0311x; 1.0311x over previous
//
#include <hip/hip_runtime.h>

// Problem shapes (fixed by reference setup_inputs)
#define B_DIM 1024
#define C_DIM 128
#define K_DIM 1024
#define E_DIM 4
#define EMBED_ELEMS (B_DIM * C_DIM * E_DIM)
#define NROWS (B_DIM * C_DIM)

typedef float f32x4 __attribute__((ext_vector_type(4)));

// f32 screen: worst-case |d32 - d64| <= ~1e-4; order flip needs f32 gap
// <= 2e-4. THR = 1e-3 gives 5x margin (validated: absmax 0.0 in R15/R16).
#define SCREEN_THR 1e-3f

// d_ws layout: [0] = atomic counter; +4 KB: idx[NROWS]; then list[NROWS].
#define WS_IDX_OFF 1024          // in ints
#define WS_LIST_OFF (1024 + NROWS)

// Grid: 5120 blocks. blockIdx%5==4 -> fill role (1024 blocks x 512 KB, pure
// dedicated store issuers); else screen role (4096 blocks, ZERO stores in
// the scan, register-cached codebook, no LDS). No LDS in the kernel at all,
// so fill blocks never limit screen residency (R17's bug #1) and fill waves
// stalling on store-queue-full is by design (they have nothing else to do).
#define GRID_BLOCKS 5120

__global__ void vq_init(int* ws) { ws[0] = 0; }

// ---------------------------------------------------------------------------
// Mixed kernel, role-specialized blocks, zero LDS.
// ---------------------------------------------------------------------------
__global__ __launch_bounds__(256) void vq_mixed_kernel(
    const float* __restrict__ cw_q,      // (B, C*E) f32
    const float* __restrict__ codebook,  // (C, K, E) f32
    float* __restrict__ out,             // [embed | one_hot]
    int* __restrict__ ws)                // counter / idx / list
{
    const int i = blockIdx.x;

    // ---------------- fill role: dedicated 512 KB zero stream ----------------
    if ((i % 5) == 4) {
        const int f = i / 5;             // 0..1023
        f32x4* dst = (f32x4*)(out + EMBED_ELEMS)
                   + (size_t)f * 32768 + threadIdx.x;
        const f32x4 z = {0.f, 0.f, 0.f, 0.f};
#pragma unroll 4
        for (int q = 0; q < 128; ++q)    // 128 x 4 KB, contiguous slab
            dst[q * 256] = z;
        return;
    }

    // ---------------- screen role: f32 top-2 argmin, register codebook ------
    const int bid  = (i / 5) * 4 + (i % 5);   // 0..4095 dense
    const int lane = threadIdx.x & 63;
    const int wave = threadIdx.x >> 6;
    const int c      = bid >> 5;         // 32 blocks per c
    const int btile  = bid & 31;
    const int b_base = btile * 32 + wave * 8;

    const float4* cb4 = (const float4*)codebook + (size_t)c * K_DIM;
    const float4* x4  = (const float4*)cw_q;    // (B, C) float4
    float4* emb4 = (float4*)out;                // (B, C) float4
    int* idx_out = ws + WS_IDX_OFF;
    int* list    = ws + WS_LIST_OFF;

    // Register-cache this c's codebook: lane owns k = j*64+lane (R1 pattern).
    float4 cb[16];
#pragma unroll
    for (int j = 0; j < 16; ++j)
        cb[j] = cb4[j * 64 + lane];

    float bsqf[16];
#pragma unroll
    for (int j = 0; j < 16; ++j)
        bsqf[j] = cb[j].x * cb[j].x + cb[j].y * cb[j].y
                + cb[j].z * cb[j].z + cb[j].w * cb[j].w;

    for (int g = 0; g < 2; ++g) {
        float x2f[4][4];
#pragma unroll
        for (int ii = 0; ii < 4; ++ii) {
            const float4 x = x4[(size_t)(b_base + g * 4 + ii) * C_DIM + c];
            x2f[ii][0] = -2.0f * x.x;  x2f[ii][1] = -2.0f * x.y;
            x2f[ii][2] = -2.0f * x.z;  x2f[ii][3] = -2.0f * x.w;
        }

        float b1[4], b2[4];  int k1[4];
#pragma unroll
        for (int ii = 0; ii < 4; ++ii) { b1[ii] = INFINITY; b2[ii] = INFINITY; k1[ii] = 0x7fffffff; }

#pragma unroll
        for (int j = 0; j < 16; ++j) {
            const float bsqj = bsqf[j];
            const int k = j * 64 + lane;
#pragma unroll
            for (int ii = 0; ii < 4; ++ii) {
                const float d = fmaf(cb[j].w, x2f[ii][3],
                                fmaf(cb[j].z, x2f[ii][2],
                                fmaf(cb[j].y, x2f[ii][1],
                                fmaf(cb[j].x, x2f[ii][0], bsqj))));
                const bool  lt1  = d < b1[ii];
                const float old1 = b1[ii];
                b1[ii] = lt1 ? d : old1;
                k1[ii] = lt1 ? k : k1[ii];
                b2[ii] = lt1 ? old1 : fminf(b2[ii], d);
            }
        }

        // Butterfly: global top-2 values + argmin index (32-bit ops).
#pragma unroll
        for (int off = 32; off >= 1; off >>= 1) {
#pragma unroll
            for (int ii = 0; ii < 4; ++ii) {
                const float ob1 = __shfl_xor(b1[ii], off);
                const int   ok1 = __shfl_xor(k1[ii], off);
                const float ob2 = __shfl_xor(b2[ii], off);
                const float mx  = fmaxf(b1[ii], ob1);
                b2[ii] = fminf(mx, fminf(b2[ii], ob2));
                if (ob1 < b1[ii] || (ob1 == b1[ii] && ok1 < k1[ii])) {
                    b1[ii] = ob1; k1[ii] = ok1;
                }
            }
        }

        // Provisional writes; ambiguous rows -> fixup list (~1%).
#pragma unroll
        for (int ii = 0; ii < 4; ++ii) {
            const int b  = b_base + g * 4 + ii;
            const int fk = k1[ii];
            const int r  = b * C_DIM + c;
            if (lane == 0) {
                emb4[r]    = cb4[fk];   // L2-hit gather (codebook is hot)
                idx_out[r] = fk;
                if (!(b2[ii] - b1[ii] > SCREEN_THR)) {
                    const int p = atomicAdd(ws, 1);
                    list[p] = r;
                }
            }
        }
    }
}

// ---------------------------------------------------------------------------
// K_fix: exact f64 re-solve for flagged rows (R3-proven path). One wave/row.
// ---------------------------------------------------------------------------
__global__ __launch_bounds__(256) void vq_fix_kernel(
    const float* __restrict__ cw_q,
    const float* __restrict__ codebook,
    float* __restrict__ out,
    int* __restrict__ ws)
{
    const int lane = threadIdx.x & 63;
    const int wave = threadIdx.x >> 6;
    const int n    = ws[0];
    const int* list = ws + WS_LIST_OFF;
    int* idx_out    = ws + WS_IDX_OFF;
    const float4* x4 = (const float4*)cw_q;
    float4* emb4     = (float4*)out;

    for (int w = blockIdx.x * 4 + wave; w < n; w += gridDim.x * 4) {
        const int r = list[w];
        const int c = r & (C_DIM - 1);
        const float4* cb4 = (const float4*)codebook + (size_t)c * K_DIM;

        const float4 x = x4[r];
        const double x20 = -2.0 * (double)x.x;
        const double x21 = -2.0 * (double)x.y;
        const double x22 = -2.0 * (double)x.z;
        const double x23 = -2.0 * (double)x.w;

        double bd = INFINITY;  int bk = 0x7fffffff;
        for (int j = 0; j < 16; ++j) {
            const float4 cb = cb4[j * 64 + lane];
            const double bx = (double)cb.x, by = (double)cb.y,
                         bz = (double)cb.z, bw = (double)cb.w;
            const double bsqj = bx * bx + by * by + bz * bz + bw * bw;
            const double d = fma(bw, x23, fma(bz, x22,
                             fma(by, x21, fma(bx, x20, bsqj))));
            const int k = j * 64 + lane;
            if (d < bd) { bd = d; bk = k; }
        }
#pragma unroll
        for (int off = 32; off >= 1; off >>= 1) {
            const double od = __shfl_xor(bd, off);
            const int    oi = __shfl_xor(bk, off);
            if (od < bd || (od == bd && oi < bk)) { bd = od; bk = oi; }
        }
        if (lane == 0) {
            emb4[r]    = cb4[bk];
            idx_out[r] = bk;
        }
    }
}

// ---------------------------------------------------------------------------
// K_ones: scatter the 131072 ones (reads final idx, after K_fix).
// ---------------------------------------------------------------------------
__global__ __launch_bounds__(256) void vq_scatter_ones(
    const int* __restrict__ ws,
    float* __restrict__ out)
{
    const int r = blockIdx.x * 256 + threadIdx.x;
    const int k = (ws + WS_IDX_OFF)[r];
    out[EMBED_ELEMS + (size_t)r * K_DIM + k] = 1.0f;
}

extern "C" void kernel_launch(void* const* d_in, const int* in_sizes, int n_in,
                              void* d_out, int out_size, void* d_ws, size_t ws_size,
                              hipStream_t stream) {
    const float* cw_q     = (const float*)d_in[0];
    const float* codebook = (const float*)d_in[1];
    float* out = (float*)d_out;
    int*   ws  = (int*)d_ws;

    vq_init<<<1, 1, 0, stream>>>(ws);
    vq_mixed_kernel<<<GRID_BLOCKS, 256, 0, stream>>>(cw_q, codebook, out, ws);
    vq_fix_kernel<<<256, 256, 0, stream>>>(cw_q, codebook, out, ws);
    vq_scatter_ones<<<NROWS / 256, 256, 0, stream>>>(ws, out);
}